// Round 10
// baseline (1343.728 us; speedup 1.0000x reference)
//
#include <hip/hip_runtime.h>

// B=4096, T=512, IN=32, H=[64,64,128], OUT=10
// 256 blocks x 1024 threads (16 waves, 4/SIMD -> latency hiding; 128 regs/wave).
// Wave-specialized, trans-balanced 2-barrier pipeline:
//   slot1: waves 0-3 (L0): layer0(t);  waves 4-7 (L1): layer1(t-1)
//   B1
//   slot2: waves 8-15 (L2): layer2(t-1) MFMA + activations
//   B2
// Weights: shared union array WS[16] (64 regs) — L0: Wih0/Whh0 (12 slots),
// L1: Wih1/Whh1 (16), L2: Whh2 (16). Wih2 staged in LDS. h states double-buffered
// in LDS. Shared AC/BI/CS keep static register demand ~125 < 128 (union trick from
// R3 — separate per-role arrays would allocate the SUM and spill).
// Per-SIMD trans floor: 80 trans-instr/slot x 8cyc = 1280 cyc/step, hidden across
// 4 resident waves. All MFMAs are builtins (compiler-managed hazards).

using f32x4  = __attribute__((ext_vector_type(4))) float;
using bf16x8 = __attribute__((ext_vector_type(8))) __bf16;

__device__ __forceinline__ __bf16 f2bf(float f) {
  unsigned u = __builtin_bit_cast(unsigned, f);
  unsigned short s = (unsigned short)((u + 0x7fffu + ((u >> 16) & 1u)) >> 16);
  return __builtin_bit_cast(__bf16, s);
}
__device__ __forceinline__ float bf2f(__bf16 b) {
  unsigned short s = __builtin_bit_cast(unsigned short, b);
  unsigned u = ((unsigned)s) << 16;
  return __builtin_bit_cast(float, u);
}
__device__ __forceinline__ float fsig(float x) {
  return __builtin_amdgcn_rcpf(1.0f + __builtin_amdgcn_exp2f(-1.442695041f * x));
}
__device__ __forceinline__ float ftanh(float x) {
  return 2.0f * __builtin_amdgcn_rcpf(1.0f + __builtin_amdgcn_exp2f(-2.885390082f * x)) - 1.0f;
}

#define MF(A, Bv, C) __builtin_amdgcn_mfma_f32_16x16x32_bf16((A), (Bv), (C), 0, 0, 0)

__device__ __forceinline__ bf16x8 ldw8(const float* p) {
  float4 v0 = *(const float4*)p;
  float4 v1 = *(const float4*)(p + 4);
  bf16x8 r;
  r[0] = f2bf(v0.x); r[1] = f2bf(v0.y); r[2] = f2bf(v0.z); r[3] = f2bf(v0.w);
  r[4] = f2bf(v1.x); r[5] = f2bf(v1.y); r[6] = f2bf(v1.z); r[7] = f2bf(v1.w);
  return r;
}

__global__ __launch_bounds__(1024, 1)
void lstm_kernel(const float* __restrict__ x,
                 const float* __restrict__ Wih0, const float* __restrict__ Whh0,
                 const float* __restrict__ bih0, const float* __restrict__ bhh0,
                 const float* __restrict__ Wih1, const float* __restrict__ Whh1,
                 const float* __restrict__ bih1, const float* __restrict__ bhh1,
                 const float* __restrict__ Wih2, const float* __restrict__ Whh2,
                 const float* __restrict__ bih2, const float* __restrict__ bhh2,
                 const float* __restrict__ Wfc, const float* __restrict__ bfc,
                 float* __restrict__ out) {
  // double-buffered h states (row stride 72/136 shorts -> benign 2-way aliasing)
  __shared__ __align__(16) __bf16 h0s[2][16][72];
  __shared__ __align__(16) __bf16 h1s[2][16][72];
  __shared__ __align__(16) __bf16 h2s[2][16][136];
  // Wih2 staged in LDS [512][72] (row pad 8)
  __shared__ __align__(16) __bf16 wih2l[512][72];

  const int tid  = threadIdx.x;
  const int w    = tid >> 6;                       // wave 0..15
  const int role = (w < 4) ? 0 : (w < 8 ? 1 : 2);  // 4 L0, 4 L1, 8 L2 waves
  const int sc   = (role == 0) ? w : (role == 1 ? (w - 4) : (w - 8));
  const int l    = tid & 63;
  const int l15  = l & 15;
  const int lg   = l >> 4;
  const int k0   = lg * 8;
  const int r0   = blockIdx.x << 4;

  for (int i = tid; i < 2 * 16 * 72; i += 1024) {
    (&h0s[0][0][0])[i] = __bf16(0.f);
    (&h1s[0][0][0])[i] = __bf16(0.f);
  }
  for (int i = tid; i < 2 * 16 * 136; i += 1024) (&h2s[0][0][0])[i] = __bf16(0.f);
  for (int i = tid; i < 512 * 64; i += 1024) {
    int row = i >> 6, col = i & 63;
    wih2l[row][col] = f2bf(Wih2[i]);
  }

  // ---- SHARED register arrays (allocation = union across roles, NOT sum) ----
  // L0: WS[3gi+0]=Wih0(K32), WS[3gi+1..2]=Whh0 kb0,1   (12 slots)
  // L1: WS[4gi+0..1]=Wih1 kb0,1; WS[4gi+2..3]=Whh1     (16 slots)
  // L2: WS[4gi+kk]=Whh2 kk0..3                          (16 slots)
  bf16x8 WS[16];
  f32x4  AC[4];
  float  BI[4];
  float  CS[4];
#pragma unroll
  for (int i = 0; i < 4; ++i) CS[i] = 0.f;

  if (role == 0) {
#pragma unroll
    for (int gi = 0; gi < 4; ++gi) {
      const int row = 16 * (4 * gi + sc) + l15;
      WS[3 * gi + 0] = ldw8(Wih0 + (size_t)row * 32 + k0);
      WS[3 * gi + 1] = ldw8(Whh0 + (size_t)row * 64 + k0);
      WS[3 * gi + 2] = ldw8(Whh0 + (size_t)row * 64 + 32 + k0);
      const int c = 64 * gi + 16 * sc + l15;
      BI[gi] = bih0[c] + bhh0[c];
    }
  } else if (role == 1) {
#pragma unroll
    for (int gi = 0; gi < 4; ++gi) {
      const int row = 16 * (4 * gi + sc) + l15;
      WS[4 * gi + 0] = ldw8(Wih1 + (size_t)row * 64 + k0);
      WS[4 * gi + 1] = ldw8(Wih1 + (size_t)row * 64 + 32 + k0);
      WS[4 * gi + 2] = ldw8(Whh1 + (size_t)row * 64 + k0);
      WS[4 * gi + 3] = ldw8(Whh1 + (size_t)row * 64 + 32 + k0);
      const int c = 64 * gi + 16 * sc + l15;
      BI[gi] = bih1[c] + bhh1[c];
    }
  } else {
#pragma unroll
    for (int gi = 0; gi < 4; ++gi) {
      const int row = 16 * (8 * gi + sc) + l15;
#pragma unroll
      for (int kk = 0; kk < 4; ++kk)
        WS[4 * gi + kk] = ldw8(Whh2 + (size_t)row * 128 + kk * 32 + k0);
      const int c = 128 * gi + 16 * sc + l15;
      BI[gi] = bih2[c] + bhh2[c];
    }
  }

  // x prefetch (L0 waves only)
  const float* xrow = x + (size_t)(r0 + l15) * 512 * 32 + k0;
  float4 nx0 = {0.f, 0.f, 0.f, 0.f}, nx1 = {0.f, 0.f, 0.f, 0.f};
  if (role == 0) { nx0 = *(const float4*)xrow; nx1 = *(const float4*)(xrow + 4); }

  __syncthreads();

  // Schedule per t (pb=t&1, rb=pb^1):
  //  slot1: L0: l0(t)   [rd h0s[rb]=h0(t-1), wr h0s[pb]=h0(t)]
  //         L1: l1(t-1) [rd h0s[rb]=h0(t-1), h1s[pb]=h1(t-2), wr h1s[rb]=h1(t-1)]
  //  B1
  //  slot2: L2: l2(t-1) [rd h1s[rb]=h1(t-1), h2s[pb]=h2(t-2); wr h2s[rb]=h2(t-1)]
  //  B2
#pragma unroll 1
  for (int t = 0; t <= 512; ++t) {
    const int pb = t & 1, rb = pb ^ 1;

    // ---------------- slot 1 ----------------
    if (role == 0) {
      if (t < 512) {
        float4 cx0 = nx0, cx1 = nx1;
        const int tn = (t + 1) & 511;  // wraparound dummy at t=511
        nx0 = *(const float4*)(xrow + (size_t)tn * 32);
        nx1 = *(const float4*)(xrow + (size_t)tn * 32 + 4);

        bf16x8 ax;
        ax[0] = f2bf(cx0.x); ax[1] = f2bf(cx0.y); ax[2] = f2bf(cx0.z); ax[3] = f2bf(cx0.w);
        ax[4] = f2bf(cx1.x); ax[5] = f2bf(cx1.y); ax[6] = f2bf(cx1.z); ax[7] = f2bf(cx1.w);

        bf16x8 a0 = *(const bf16x8*)&h0s[rb][l15][k0];
        bf16x8 a1 = *(const bf16x8*)&h0s[rb][l15][32 + k0];
#pragma unroll
        for (int gi = 0; gi < 4; ++gi) {
          f32x4 a = {BI[gi], BI[gi], BI[gi], BI[gi]};
          a = MF(ax, WS[3 * gi + 0], a);
          a = MF(a0, WS[3 * gi + 1], a);
          a = MF(a1, WS[3 * gi + 2], a);
          AC[gi] = a;
        }
#pragma unroll
        for (int j = 0; j < 4; ++j) {
          float nc = fsig(AC[1][j]) * CS[j] + fsig(AC[0][j]) * ftanh(AC[2][j]);
          CS[j] = nc;
          h0s[pb][4 * lg + j][16 * sc + l15] = f2bf(fsig(AC[3][j]) * ftanh(nc));
        }
      }
    } else if (role == 1) {
      if (t >= 1) {
        bf16x8 a0 = *(const bf16x8*)&h0s[rb][l15][k0];       // h0(t-1)
        bf16x8 a1 = *(const bf16x8*)&h0s[rb][l15][32 + k0];
        bf16x8 b0 = *(const bf16x8*)&h1s[pb][l15][k0];       // h1(t-2)
        bf16x8 b1 = *(const bf16x8*)&h1s[pb][l15][32 + k0];
#pragma unroll
        for (int gi = 0; gi < 4; ++gi) {
          f32x4 a = {BI[gi], BI[gi], BI[gi], BI[gi]};
          a = MF(a0, WS[4 * gi + 0], a);
          a = MF(a1, WS[4 * gi + 1], a);
          a = MF(b0, WS[4 * gi + 2], a);
          a = MF(b1, WS[4 * gi + 3], a);
          AC[gi] = a;
        }
#pragma unroll
        for (int j = 0; j < 4; ++j) {
          float nc = fsig(AC[1][j]) * CS[j] + fsig(AC[0][j]) * ftanh(AC[2][j]);
          CS[j] = nc;
          h1s[rb][4 * lg + j][16 * sc + l15] = f2bf(fsig(AC[3][j]) * ftanh(nc));
        }
      }
    }
    __syncthreads();  // B1

    // ---------------- slot 2 ----------------
    if (role == 2 && t >= 1) {
      bf16x8 b0 = *(const bf16x8*)&h1s[rb][l15][k0];         // h1(t-1)
      bf16x8 b1 = *(const bf16x8*)&h1s[rb][l15][32 + k0];
      bf16x8 d0 = *(const bf16x8*)&h2s[pb][l15][k0];         // h2(t-2)
      bf16x8 d1 = *(const bf16x8*)&h2s[pb][l15][32 + k0];
      bf16x8 d2 = *(const bf16x8*)&h2s[pb][l15][64 + k0];
      bf16x8 d3 = *(const bf16x8*)&h2s[pb][l15][96 + k0];
#pragma unroll
      for (int gi = 0; gi < 4; ++gi) {
        const int tile = 8 * gi + sc;
        bf16x8 wa0 = *(const bf16x8*)&wih2l[16 * tile + l15][k0];
        bf16x8 wa1 = *(const bf16x8*)&wih2l[16 * tile + l15][32 + k0];
        f32x4 a = {BI[gi], BI[gi], BI[gi], BI[gi]};
        a = MF(b0, wa0, a);
        a = MF(b1, wa1, a);
        a = MF(d0, WS[4 * gi + 0], a);
        a = MF(d1, WS[4 * gi + 1], a);
        a = MF(d2, WS[4 * gi + 2], a);
        a = MF(d3, WS[4 * gi + 3], a);
        AC[gi] = a;
      }
#pragma unroll
      for (int j = 0; j < 4; ++j) {
        float nc = fsig(AC[1][j]) * CS[j] + fsig(AC[0][j]) * ftanh(AC[2][j]);
        CS[j] = nc;
        h2s[rb][4 * lg + j][16 * sc + l15] = f2bf(fsig(AC[3][j]) * ftanh(nc));
      }
    }
    __syncthreads();  // B2
  }

  // ---- final FC: out = h2(511) @ Wfc^T + bfc;  h2(511) in buffer 1 ----
  if (tid < 160) {
    const int r = tid / 10, o = tid - r * 10;
    float sum = bfc[o];
    for (int u = 0; u < 128; ++u) sum += bf2f(h2s[1][r][u]) * Wfc[o * 128 + u];
    out[(size_t)(r0 + r) * 10 + o] = sum;
  }
}

extern "C" void kernel_launch(void* const* d_in, const int* in_sizes, int n_in,
                              void* d_out, int out_size, void* d_ws, size_t ws_size,
                              hipStream_t stream) {
  const float* x    = (const float*)d_in[0];
  const float* Wih0 = (const float*)d_in[1];
  const float* Whh0 = (const float*)d_in[2];
  const float* bih0 = (const float*)d_in[3];
  const float* bhh0 = (const float*)d_in[4];
  const float* Wih1 = (const float*)d_in[5];
  const float* Whh1 = (const float*)d_in[6];
  const float* bih1 = (const float*)d_in[7];
  const float* bhh1 = (const float*)d_in[8];
  const float* Wih2 = (const float*)d_in[9];
  const float* Whh2 = (const float*)d_in[10];
  const float* bih2 = (const float*)d_in[11];
  const float* bhh2 = (const float*)d_in[12];
  const float* Wfc  = (const float*)d_in[13];
  const float* bfc  = (const float*)d_in[14];

  lstm_kernel<<<256, 1024, 0, stream>>>(x, Wih0, Whh0, bih0, bhh0,
                                        Wih1, Whh1, bih1, bhh1,
                                        Wih2, Whh2, bih2, bhh2,
                                        Wfc, bfc, (float*)d_out);
}

// Round 11
// 1084.942 us; speedup vs baseline: 1.2385x; 1.2385x over previous
//
#include <hip/hip_runtime.h>

// B=4096, T=512, IN=32, H=[64,64,128], OUT=10
// 256 blocks x 512 threads (8 waves, 2/SIMD -> G01/G23 waves co-resident per SIMD,
// mutual stall hiding). Wave-specialized pipeline (R7 schedule, proven correct):
//   slot1: waves 0-3 (G01): layer0(t);  waves 4-7 (G23): layer2(t-1) MFMA
//   B1
//   slot2: G01: layer1(t);              G23: layer2(t-1) activations
//   B2
// KEY (R11): ALL register-resident weights live in AGPRs via PIN_A ("+a" empty asm,
// zero instructions -> zero hazards; mechanism proven R9). Shared union array AG[32]
// = 128 AGPRs/wave: G01 uses 28 slots (Wih0/Whh0/Wih1/Whh1), G23 all 32 (Whh2).
// This escapes the compiler's 128-arch-VGPR cap at 512 threads (allocator targets
// 65536 regs/block = 2 blocks/CU; arch-V demand ~100 < 128 -> no in-loop spills,
// AGPRs don't count against the 128). Wih2 in LDS. MFMAs are builtins (srcB is
// AV-class -> reads AGPR directly; compiler-managed hazards).

using f32x4  = __attribute__((ext_vector_type(4))) float;
using bf16x8 = __attribute__((ext_vector_type(8))) __bf16;

__device__ __forceinline__ __bf16 f2bf(float f) {
  unsigned u = __builtin_bit_cast(unsigned, f);
  unsigned short s = (unsigned short)((u + 0x7fffu + ((u >> 16) & 1u)) >> 16);
  return __builtin_bit_cast(__bf16, s);
}
__device__ __forceinline__ float bf2f(__bf16 b) {
  unsigned short s = __builtin_bit_cast(unsigned short, b);
  unsigned u = ((unsigned)s) << 16;
  return __builtin_bit_cast(float, u);
}
__device__ __forceinline__ float fsig(float x) {
  return __builtin_amdgcn_rcpf(1.0f + __builtin_amdgcn_exp2f(-1.442695041f * x));
}
__device__ __forceinline__ float ftanh(float x) {
  return 2.0f * __builtin_amdgcn_rcpf(1.0f + __builtin_amdgcn_exp2f(-2.885390082f * x)) - 1.0f;
}

#define MF(A, Bv, C) __builtin_amdgcn_mfma_f32_16x16x32_bf16((A), (Bv), (C), 0, 0, 0)
// Pin a bf16x8 (4 regs) into AGPRs; no instructions emitted -> no hazard exposure.
#define PIN_A(v) asm volatile("" : "+a"(v))

__device__ __forceinline__ bf16x8 ldw8(const float* p) {
  float4 v0 = *(const float4*)p;
  float4 v1 = *(const float4*)(p + 4);
  bf16x8 r;
  r[0] = f2bf(v0.x); r[1] = f2bf(v0.y); r[2] = f2bf(v0.z); r[3] = f2bf(v0.w);
  r[4] = f2bf(v1.x); r[5] = f2bf(v1.y); r[6] = f2bf(v1.z); r[7] = f2bf(v1.w);
  return r;
}

__global__ __launch_bounds__(512)
void lstm_kernel(const float* __restrict__ x,
                 const float* __restrict__ Wih0, const float* __restrict__ Whh0,
                 const float* __restrict__ bih0, const float* __restrict__ bhh0,
                 const float* __restrict__ Wih1, const float* __restrict__ Whh1,
                 const float* __restrict__ bih1, const float* __restrict__ bhh1,
                 const float* __restrict__ Wih2, const float* __restrict__ Whh2,
                 const float* __restrict__ bih2, const float* __restrict__ bhh2,
                 const float* __restrict__ Wfc, const float* __restrict__ bfc,
                 float* __restrict__ out) {
  // double-buffered h states (stride 72/136 shorts -> 2-way bank aliasing only)
  __shared__ __align__(16) __bf16 h0s[2][16][72];
  __shared__ __align__(16) __bf16 h1s[2][16][72];
  __shared__ __align__(16) __bf16 h2s[2][16][136];
  // Wih2 staged in LDS [512][72] (row pad 8)
  __shared__ __align__(16) __bf16 wih2l[512][72];

  const int tid = threadIdx.x;
  const int w   = tid >> 6;      // wave 0..7
  const bool g01 = (w < 4);
  const int gw  = w & 3;         // wave id within group, 0..3
  const int l   = tid & 63;
  const int l15 = l & 15;
  const int lg  = l >> 4;
  const int k0  = lg * 8;
  const int r0  = blockIdx.x << 4;

  for (int i = tid; i < 2 * 16 * 72; i += 512) {
    (&h0s[0][0][0])[i] = __bf16(0.f);
    (&h1s[0][0][0])[i] = __bf16(0.f);
  }
  for (int i = tid; i < 2 * 16 * 136; i += 512) (&h2s[0][0][0])[i] = __bf16(0.f);
  for (int i = tid; i < 512 * 64; i += 512) {
    int row = i >> 6, col = i & 63;
    wih2l[row][col] = f2bf(Wih2[i]);
  }

  // ---- SHARED weight array (union across roles), pinned to AGPRs ----
  // G01: AG[0..3]=Wih0, AG[4..11]=Whh0, AG[12..19]=Wih1, AG[20..27]=Whh1
  // G23: AG[0..31]=Whh2 (s,gi,kk -> 16s+4gi+kk)
  bf16x8 AG[32];
#pragma unroll
  for (int i = 0; i < 32; ++i) AG[i] = bf16x8{};
  f32x4  AC[8];     // G01: AC[0..3] reused l0 then l1; G23: AC[4s+gi], live across B1
  float  BI[8];     // G01: bias0[gi], bias1[4+gi]; G23: bias2 -> 4s+gi
  float  CS[8];     // G01: c0[j], c1[4+j]; G23: c2 -> 4s+j
#pragma unroll
  for (int i = 0; i < 8; ++i) CS[i] = 0.f;

  if (g01) {
#pragma unroll
    for (int gi = 0; gi < 4; ++gi) {
      const int row = 16 * (4 * gi + gw) + l15;
      AG[gi] = ldw8(Wih0 + (size_t)row * 32 + k0);
#pragma unroll
      for (int kb = 0; kb < 2; ++kb) {
        AG[4 + 2 * gi + kb]  = ldw8(Whh0 + (size_t)row * 64 + kb * 32 + k0);
        AG[12 + 2 * gi + kb] = ldw8(Wih1 + (size_t)row * 64 + kb * 32 + k0);
        AG[20 + 2 * gi + kb] = ldw8(Whh1 + (size_t)row * 64 + kb * 32 + k0);
      }
      const int c01 = 64 * gi + 16 * gw + l15;
      BI[gi]     = bih0[c01] + bhh0[c01];
      BI[4 + gi] = bih1[c01] + bhh1[c01];
    }
  } else {
#pragma unroll
    for (int s = 0; s < 2; ++s)
#pragma unroll
      for (int gi = 0; gi < 4; ++gi) {
        const int row = 16 * (8 * gi + 2 * gw + s) + l15;
#pragma unroll
        for (int kk = 0; kk < 4; ++kk)
          AG[16 * s + 4 * gi + kk] = ldw8(Whh2 + (size_t)row * 128 + kk * 32 + k0);
        const int c2 = 128 * gi + 32 * gw + 16 * s + l15;
        BI[4 * s + gi] = bih2[c2] + bhh2[c2];
      }
  }
  // Pin the whole union into AGPRs (128 AGPRs/wave).
#pragma unroll
  for (int i = 0; i < 32; ++i) PIN_A(AG[i]);

  const float* xrow = x + (size_t)(r0 + l15) * 512 * 32 + k0;
  float4 nx0 = {0.f, 0.f, 0.f, 0.f}, nx1 = {0.f, 0.f, 0.f, 0.f};
  if (g01) { nx0 = *(const float4*)xrow; nx1 = *(const float4*)(xrow + 4); }

  __syncthreads();

#pragma unroll 1
  for (int t = 0; t <= 512; ++t) {
    const int pb = t & 1, rb = pb ^ 1;

    // ---------------- slot 1 ----------------
    if (g01) {
      if (t < 512) {
        // layer0(t): h0(t) = cell(x(t), h0(t-1))
        float4 cx0 = nx0, cx1 = nx1;
        const int tn = (t + 1) & 511;  // wraparound dummy at t=511
        nx0 = *(const float4*)(xrow + (size_t)tn * 32);
        nx1 = *(const float4*)(xrow + (size_t)tn * 32 + 4);

        bf16x8 ax;
        ax[0] = f2bf(cx0.x); ax[1] = f2bf(cx0.y); ax[2] = f2bf(cx0.z); ax[3] = f2bf(cx0.w);
        ax[4] = f2bf(cx1.x); ax[5] = f2bf(cx1.y); ax[6] = f2bf(cx1.z); ax[7] = f2bf(cx1.w);

        bf16x8 a0 = *(const bf16x8*)&h0s[rb][l15][k0];
        bf16x8 a1 = *(const bf16x8*)&h0s[rb][l15][32 + k0];
#pragma unroll
        for (int gi = 0; gi < 4; ++gi) {
          f32x4 a = {BI[gi], BI[gi], BI[gi], BI[gi]};
          a = MF(ax, AG[gi], a);
          a = MF(a0, AG[4 + 2 * gi], a);
          a = MF(a1, AG[5 + 2 * gi], a);
          AC[gi] = a;
        }
#pragma unroll
        for (int j = 0; j < 4; ++j) {
          float nc = fsig(AC[1][j]) * CS[j] + fsig(AC[0][j]) * ftanh(AC[2][j]);
          CS[j] = nc;
          h0s[pb][4 * lg + j][16 * gw + l15] = f2bf(fsig(AC[3][j]) * ftanh(nc));
        }
      }
    } else {
      if (t >= 1) {
        // layer2(t-1) MFMA: gates = Wih2*h1(t-1) + Whh2*h2(t-2) + b
        bf16x8 b0 = *(const bf16x8*)&h1s[rb][l15][k0];
        bf16x8 b1 = *(const bf16x8*)&h1s[rb][l15][32 + k0];
        bf16x8 d0 = *(const bf16x8*)&h2s[pb][l15][k0];
        bf16x8 d1 = *(const bf16x8*)&h2s[pb][l15][32 + k0];
        bf16x8 d2 = *(const bf16x8*)&h2s[pb][l15][64 + k0];
        bf16x8 d3 = *(const bf16x8*)&h2s[pb][l15][96 + k0];
#pragma unroll
        for (int s = 0; s < 2; ++s)
#pragma unroll
          for (int gi = 0; gi < 4; ++gi) {
            const int tile = 8 * gi + 2 * gw + s;
            bf16x8 wa0 = *(const bf16x8*)&wih2l[16 * tile + l15][k0];
            bf16x8 wa1 = *(const bf16x8*)&wih2l[16 * tile + l15][32 + k0];
            f32x4 a = {BI[4 * s + gi], BI[4 * s + gi], BI[4 * s + gi], BI[4 * s + gi]};
            a = MF(b0, wa0, a);
            a = MF(b1, wa1, a);
            a = MF(d0, AG[16 * s + 4 * gi + 0], a);
            a = MF(d1, AG[16 * s + 4 * gi + 1], a);
            a = MF(d2, AG[16 * s + 4 * gi + 2], a);
            a = MF(d3, AG[16 * s + 4 * gi + 3], a);
            AC[4 * s + gi] = a;
          }
      }
    }
    __syncthreads();  // B1: h0(t) visible to G01-l1

    // ---------------- slot 2 ----------------
    if (g01) {
      if (t < 512) {
        // layer1(t): h1(t) = cell(h0(t), h1(t-1))
        bf16x8 a0 = *(const bf16x8*)&h0s[pb][l15][k0];
        bf16x8 a1 = *(const bf16x8*)&h0s[pb][l15][32 + k0];
        bf16x8 b0 = *(const bf16x8*)&h1s[rb][l15][k0];
        bf16x8 b1 = *(const bf16x8*)&h1s[rb][l15][32 + k0];
#pragma unroll
        for (int gi = 0; gi < 4; ++gi) {
          f32x4 a = {BI[4 + gi], BI[4 + gi], BI[4 + gi], BI[4 + gi]};
          a = MF(a0, AG[12 + 2 * gi], a);
          a = MF(a1, AG[13 + 2 * gi], a);
          a = MF(b0, AG[20 + 2 * gi], a);
          a = MF(b1, AG[21 + 2 * gi], a);
          AC[gi] = a;
        }
#pragma unroll
        for (int j = 0; j < 4; ++j) {
          float nc = fsig(AC[1][j]) * CS[4 + j] + fsig(AC[0][j]) * ftanh(AC[2][j]);
          CS[4 + j] = nc;
          h1s[pb][4 * lg + j][16 * gw + l15] = f2bf(fsig(AC[3][j]) * ftanh(nc));
        }
      }
    } else {
      if (t >= 1) {
        // layer2(t-1) activations -> h2(t-1)
#pragma unroll
        for (int s = 0; s < 2; ++s)
#pragma unroll
          for (int j = 0; j < 4; ++j) {
            float nc = fsig(AC[4 * s + 1][j]) * CS[4 * s + j]
                     + fsig(AC[4 * s + 0][j]) * ftanh(AC[4 * s + 2][j]);
            CS[4 * s + j] = nc;
            h2s[rb][4 * lg + j][32 * gw + 16 * s + l15] = f2bf(fsig(AC[4 * s + 3][j]) * ftanh(nc));
          }
      }
    }
    __syncthreads();  // B2: h1(t), h2(t-1) visible
  }

  // ---- final FC: out = h2(511) @ Wfc^T + bfc;  h2(511) is in buffer 1 ----
  if (tid < 160) {
    const int r = tid / 10, o = tid - r * 10;
    float sum = bfc[o];
    for (int u = 0; u < 128; ++u) sum += bf2f(h2s[1][r][u]) * Wfc[o * 128 + u];
    out[(size_t)(r0 + r) * 10 + o] = sum;
  }
}

extern "C" void kernel_launch(void* const* d_in, const int* in_sizes, int n_in,
                              void* d_out, int out_size, void* d_ws, size_t ws_size,
                              hipStream_t stream) {
  const float* x    = (const float*)d_in[0];
  const float* Wih0 = (const float*)d_in[1];
  const float* Whh0 = (const float*)d_in[2];
  const float* bih0 = (const float*)d_in[3];
  const float* bhh0 = (const float*)d_in[4];
  const float* Wih1 = (const float*)d_in[5];
  const float* Whh1 = (const float*)d_in[6];
  const float* bih1 = (const float*)d_in[7];
  const float* bhh1 = (const float*)d_in[8];
  const float* Wih2 = (const float*)d_in[9];
  const float* Whh2 = (const float*)d_in[10];
  const float* bih2 = (const float*)d_in[11];
  const float* bhh2 = (const float*)d_in[12];
  const float* Wfc  = (const float*)d_in[13];
  const float* bfc  = (const float*)d_in[14];

  lstm_kernel<<<256, 512, 0, stream>>>(x, Wih0, Whh0, bih0, bhh0,
                                       Wih1, Whh1, bih1, bhh1,
                                       Wih2, Whh2, bih2, bhh2,
                                       Wfc, bfc, (float*)d_out);
}

// Round 12
// 960.149 us; speedup vs baseline: 1.3995x; 1.1300x over previous
//
#include <hip/hip_runtime.h>

// B=4096, T=512, IN=32, H=[64,64,128], OUT=10
// 256 blocks x 512 threads (8 waves, 2/SIMD). Wave-specialized pipeline (R7/R11):
//   slot1: waves 0-3 (G01): layer0(t);  waves 4-7 (G23): layer2(t-1) MFMA
//   B1
//   slot2: G01: layer1(t);              G23: layer2(t-1) activations
//   B2
// Weights in AGPRs via PIN_A union AG[32] (R11 mechanism, builtins read AGPR srcB).
// R12: kernel is trans-issue-bound (VALUBusy 67% ~= 160 trans/SIMD/step @ 1/4 rate).
// Cut non-trans VALU: (a) native bf16 casts (1 instr vs 5-op manual RTNE),
// (b) biases pre-scaled and folded into the exp2 argument via fma -> MFMA C-init is
// a hoistable zero vector instead of 32 unhoistable bias-splat movs/thread/step.

using f32x4  = __attribute__((ext_vector_type(4))) float;
using bf16x8 = __attribute__((ext_vector_type(8))) __bf16;

#define KS (-1.442695041f)   // -log2(e)
#define KT (-2.885390082f)   // -2*log2(e)

__device__ __forceinline__ float bf2f(__bf16 b) {
  unsigned short s = __builtin_bit_cast(unsigned short, b);
  unsigned u = ((unsigned)s) << 16;
  return __builtin_bit_cast(float, u);
}
// sigmoid(x+b) where u = KS*x + KS*b (bias pre-scaled)
__device__ __forceinline__ float sig_u(float u) {
  return __builtin_amdgcn_rcpf(1.0f + __builtin_amdgcn_exp2f(u));
}
// tanh(x+b) where u = KT*x + KT*b
__device__ __forceinline__ float tanh_u(float u) {
  return 2.0f * __builtin_amdgcn_rcpf(1.0f + __builtin_amdgcn_exp2f(u)) - 1.0f;
}

#define MF(A, Bv, C) __builtin_amdgcn_mfma_f32_16x16x32_bf16((A), (Bv), (C), 0, 0, 0)
// Pin a bf16x8 (4 regs) into AGPRs; no instructions emitted -> no hazard exposure.
#define PIN_A(v) asm volatile("" : "+a"(v))

__device__ __forceinline__ bf16x8 ldw8(const float* p) {
  float4 v0 = *(const float4*)p;
  float4 v1 = *(const float4*)(p + 4);
  bf16x8 r;
  r[0] = (__bf16)v0.x; r[1] = (__bf16)v0.y; r[2] = (__bf16)v0.z; r[3] = (__bf16)v0.w;
  r[4] = (__bf16)v1.x; r[5] = (__bf16)v1.y; r[6] = (__bf16)v1.z; r[7] = (__bf16)v1.w;
  return r;
}

__global__ __launch_bounds__(512)
void lstm_kernel(const float* __restrict__ x,
                 const float* __restrict__ Wih0, const float* __restrict__ Whh0,
                 const float* __restrict__ bih0, const float* __restrict__ bhh0,
                 const float* __restrict__ Wih1, const float* __restrict__ Whh1,
                 const float* __restrict__ bih1, const float* __restrict__ bhh1,
                 const float* __restrict__ Wih2, const float* __restrict__ Whh2,
                 const float* __restrict__ bih2, const float* __restrict__ bhh2,
                 const float* __restrict__ Wfc, const float* __restrict__ bfc,
                 float* __restrict__ out) {
  __shared__ __align__(16) __bf16 h0s[2][16][72];
  __shared__ __align__(16) __bf16 h1s[2][16][72];
  __shared__ __align__(16) __bf16 h2s[2][16][136];
  __shared__ __align__(16) __bf16 wih2l[512][72];

  const int tid = threadIdx.x;
  const int w   = tid >> 6;      // wave 0..7
  const bool g01 = (w < 4);
  const int gw  = w & 3;
  const int l   = tid & 63;
  const int l15 = l & 15;
  const int lg  = l >> 4;
  const int k0  = lg * 8;
  const int r0  = blockIdx.x << 4;

  for (int i = tid; i < 2 * 16 * 72; i += 512) {
    (&h0s[0][0][0])[i] = __bf16(0.f);
    (&h1s[0][0][0])[i] = __bf16(0.f);
  }
  for (int i = tid; i < 2 * 16 * 136; i += 512) (&h2s[0][0][0])[i] = __bf16(0.f);
  for (int i = tid; i < 512 * 64; i += 512) {
    int row = i >> 6, col = i & 63;
    wih2l[row][col] = (__bf16)Wih2[i];
  }

  // ---- SHARED weight array (union across roles), pinned to AGPRs ----
  // G01: AG[0..3]=Wih0, AG[4..11]=Whh0, AG[12..19]=Wih1, AG[20..27]=Whh1
  // G23: AG[0..31]=Whh2 (s,gi,kk -> 16s+4gi+kk)
  bf16x8 AG[32];
#pragma unroll
  for (int i = 0; i < 32; ++i) AG[i] = bf16x8{};
  f32x4  AC[8];     // G01: AC[0..3] reused l0 then l1; G23: AC[4s+gi], live across B1
  float  BI[8];     // PRE-SCALED biases: gate gi==2 (g): KT*b, else KS*b
  float  CS[8];     // cell states
#pragma unroll
  for (int i = 0; i < 8; ++i) CS[i] = 0.f;

  if (g01) {
#pragma unroll
    for (int gi = 0; gi < 4; ++gi) {
      const int row = 16 * (4 * gi + gw) + l15;
      AG[gi] = ldw8(Wih0 + (size_t)row * 32 + k0);
#pragma unroll
      for (int kb = 0; kb < 2; ++kb) {
        AG[4 + 2 * gi + kb]  = ldw8(Whh0 + (size_t)row * 64 + kb * 32 + k0);
        AG[12 + 2 * gi + kb] = ldw8(Wih1 + (size_t)row * 64 + kb * 32 + k0);
        AG[20 + 2 * gi + kb] = ldw8(Whh1 + (size_t)row * 64 + kb * 32 + k0);
      }
      const float sc = (gi == 2) ? KT : KS;
      const int c01 = 64 * gi + 16 * gw + l15;
      BI[gi]     = sc * (bih0[c01] + bhh0[c01]);
      BI[4 + gi] = sc * (bih1[c01] + bhh1[c01]);
    }
  } else {
#pragma unroll
    for (int s = 0; s < 2; ++s)
#pragma unroll
      for (int gi = 0; gi < 4; ++gi) {
        const int row = 16 * (8 * gi + 2 * gw + s) + l15;
#pragma unroll
        for (int kk = 0; kk < 4; ++kk)
          AG[16 * s + 4 * gi + kk] = ldw8(Whh2 + (size_t)row * 128 + kk * 32 + k0);
        const float sc = (gi == 2) ? KT : KS;
        const int c2 = 128 * gi + 32 * gw + 16 * s + l15;
        BI[4 * s + gi] = sc * (bih2[c2] + bhh2[c2]);
      }
  }
#pragma unroll
  for (int i = 0; i < 32; ++i) PIN_A(AG[i]);

  const float* xrow = x + (size_t)(r0 + l15) * 512 * 32 + k0;
  float4 nx0 = {0.f, 0.f, 0.f, 0.f}, nx1 = {0.f, 0.f, 0.f, 0.f};
  if (g01) { nx0 = *(const float4*)xrow; nx1 = *(const float4*)(xrow + 4); }

  const f32x4 Z0 = {0.f, 0.f, 0.f, 0.f};  // loop-invariant MFMA C-init

  __syncthreads();

#pragma unroll 1
  for (int t = 0; t <= 512; ++t) {
    const int pb = t & 1, rb = pb ^ 1;

    // ---------------- slot 1 ----------------
    if (g01) {
      if (t < 512) {
        // layer0(t): h0(t) = cell(x(t), h0(t-1))
        float4 cx0 = nx0, cx1 = nx1;
        const int tn = (t + 1) & 511;
        nx0 = *(const float4*)(xrow + (size_t)tn * 32);
        nx1 = *(const float4*)(xrow + (size_t)tn * 32 + 4);

        bf16x8 ax;
        ax[0] = (__bf16)cx0.x; ax[1] = (__bf16)cx0.y; ax[2] = (__bf16)cx0.z; ax[3] = (__bf16)cx0.w;
        ax[4] = (__bf16)cx1.x; ax[5] = (__bf16)cx1.y; ax[6] = (__bf16)cx1.z; ax[7] = (__bf16)cx1.w;

        bf16x8 a0 = *(const bf16x8*)&h0s[rb][l15][k0];
        bf16x8 a1 = *(const bf16x8*)&h0s[rb][l15][32 + k0];
#pragma unroll
        for (int gi = 0; gi < 4; ++gi) {
          f32x4 a = Z0;
          a = MF(ax, AG[gi], a);
          a = MF(a0, AG[4 + 2 * gi], a);
          a = MF(a1, AG[5 + 2 * gi], a);
          AC[gi] = a;
        }
#pragma unroll
        for (int j = 0; j < 4; ++j) {
          float si = sig_u (fmaf(KS, AC[0][j], BI[0]));
          float sf = sig_u (fmaf(KS, AC[1][j], BI[1]));
          float tg = tanh_u(fmaf(KT, AC[2][j], BI[2]));
          float so = sig_u (fmaf(KS, AC[3][j], BI[3]));
          float nc = sf * CS[j] + si * tg;
          CS[j] = nc;
          h0s[pb][4 * lg + j][16 * gw + l15] = (__bf16)(so * tanh_u(KT * nc));
        }
      }
    } else {
      if (t >= 1) {
        // layer2(t-1) MFMA: gates = Wih2*h1(t-1) + Whh2*h2(t-2)
        bf16x8 b0 = *(const bf16x8*)&h1s[rb][l15][k0];
        bf16x8 b1 = *(const bf16x8*)&h1s[rb][l15][32 + k0];
        bf16x8 d0 = *(const bf16x8*)&h2s[pb][l15][k0];
        bf16x8 d1 = *(const bf16x8*)&h2s[pb][l15][32 + k0];
        bf16x8 d2 = *(const bf16x8*)&h2s[pb][l15][64 + k0];
        bf16x8 d3 = *(const bf16x8*)&h2s[pb][l15][96 + k0];
#pragma unroll
        for (int s = 0; s < 2; ++s)
#pragma unroll
          for (int gi = 0; gi < 4; ++gi) {
            const int tile = 8 * gi + 2 * gw + s;
            bf16x8 wa0 = *(const bf16x8*)&wih2l[16 * tile + l15][k0];
            bf16x8 wa1 = *(const bf16x8*)&wih2l[16 * tile + l15][32 + k0];
            f32x4 a = Z0;
            a = MF(b0, wa0, a);
            a = MF(b1, wa1, a);
            a = MF(d0, AG[16 * s + 4 * gi + 0], a);
            a = MF(d1, AG[16 * s + 4 * gi + 1], a);
            a = MF(d2, AG[16 * s + 4 * gi + 2], a);
            a = MF(d3, AG[16 * s + 4 * gi + 3], a);
            AC[4 * s + gi] = a;
          }
      }
    }
    __syncthreads();  // B1: h0(t) visible to G01-l1

    // ---------------- slot 2 ----------------
    if (g01) {
      if (t < 512) {
        // layer1(t): h1(t) = cell(h0(t), h1(t-1))
        bf16x8 a0 = *(const bf16x8*)&h0s[pb][l15][k0];
        bf16x8 a1 = *(const bf16x8*)&h0s[pb][l15][32 + k0];
        bf16x8 b0 = *(const bf16x8*)&h1s[rb][l15][k0];
        bf16x8 b1 = *(const bf16x8*)&h1s[rb][l15][32 + k0];
#pragma unroll
        for (int gi = 0; gi < 4; ++gi) {
          f32x4 a = Z0;
          a = MF(a0, AG[12 + 2 * gi], a);
          a = MF(a1, AG[13 + 2 * gi], a);
          a = MF(b0, AG[20 + 2 * gi], a);
          a = MF(b1, AG[21 + 2 * gi], a);
          AC[gi] = a;
        }
#pragma unroll
        for (int j = 0; j < 4; ++j) {
          float si = sig_u (fmaf(KS, AC[0][j], BI[4]));
          float sf = sig_u (fmaf(KS, AC[1][j], BI[5]));
          float tg = tanh_u(fmaf(KT, AC[2][j], BI[6]));
          float so = sig_u (fmaf(KS, AC[3][j], BI[7]));
          float nc = sf * CS[4 + j] + si * tg;
          CS[4 + j] = nc;
          h1s[pb][4 * lg + j][16 * gw + l15] = (__bf16)(so * tanh_u(KT * nc));
        }
      }
    } else {
      if (t >= 1) {
        // layer2(t-1) activations -> h2(t-1)
#pragma unroll
        for (int s = 0; s < 2; ++s)
#pragma unroll
          for (int j = 0; j < 4; ++j) {
            float si = sig_u (fmaf(KS, AC[4 * s + 0][j], BI[4 * s + 0]));
            float sf = sig_u (fmaf(KS, AC[4 * s + 1][j], BI[4 * s + 1]));
            float tg = tanh_u(fmaf(KT, AC[4 * s + 2][j], BI[4 * s + 2]));
            float so = sig_u (fmaf(KS, AC[4 * s + 3][j], BI[4 * s + 3]));
            float nc = sf * CS[4 * s + j] + si * tg;
            CS[4 * s + j] = nc;
            h2s[rb][4 * lg + j][32 * gw + 16 * s + l15] = (__bf16)(so * tanh_u(KT * nc));
          }
      }
    }
    __syncthreads();  // B2: h1(t), h2(t-1) visible
  }

  // ---- final FC: out = h2(511) @ Wfc^T + bfc;  h2(511) is in buffer 1 ----
  if (tid < 160) {
    const int r = tid / 10, o = tid - r * 10;
    float sum = bfc[o];
    for (int u = 0; u < 128; ++u) sum += bf2f(h2s[1][r][u]) * Wfc[o * 128 + u];
    out[(size_t)(r0 + r) * 10 + o] = sum;
  }
}

extern "C" void kernel_launch(void* const* d_in, const int* in_sizes, int n_in,
                              void* d_out, int out_size, void* d_ws, size_t ws_size,
                              hipStream_t stream) {
  const float* x    = (const float*)d_in[0];
  const float* Wih0 = (const float*)d_in[1];
  const float* Whh0 = (const float*)d_in[2];
  const float* bih0 = (const float*)d_in[3];
  const float* bhh0 = (const float*)d_in[4];
  const float* Wih1 = (const float*)d_in[5];
  const float* Whh1 = (const float*)d_in[6];
  const float* bih1 = (const float*)d_in[7];
  const float* bhh1 = (const float*)d_in[8];
  const float* Wih2 = (const float*)d_in[9];
  const float* Whh2 = (const float*)d_in[10];
  const float* bih2 = (const float*)d_in[11];
  const float* bhh2 = (const float*)d_in[12];
  const float* Wfc  = (const float*)d_in[13];
  const float* bfc  = (const float*)d_in[14];

  lstm_kernel<<<256, 512, 0, stream>>>(x, Wih0, Whh0, bih0, bhh0,
                                       Wih1, Whh1, bih1, bhh1,
                                       Wih2, Whh2, bih2, bhh2,
                                       Wfc, bfc, (float*)d_out);
}

// Round 13
// 957.826 us; speedup vs baseline: 1.4029x; 1.0024x over previous
//
#include <hip/hip_runtime.h>

// B=4096, T=512, IN=32, H=[64,64,128], OUT=10
// 256 blocks x 512 threads (8 waves, 2/SIMD). Wave-specialized pipeline:
//   slot1: G01 (waves 0-3): layer0(t) MFMA+acts
//          G23 (waves 4-7): layer2(t-1) s=0 MFMA -> s=0 acts+write -> s=1 MFMA
//   B1
//   slot2: G01: layer1(t) MFMA+acts;   G23: s=1 acts+write
//   B2
// R13: trans-slot balancing. R12 had 40/120 trans per slot per SIMD (G23's 80
// all in slot2); barriers make each slot as long as its max wave -> slot2 was
// 1920 cyc of serialized trans. Moving s=0's acts into slot1 gives 80/80.
// Weights in AGPRs (PIN_A union AG[32], R11); biases pre-scaled into exp2 args
// (R12); native bf16 casts; builtin MFMAs only (compiler-managed hazards).

using f32x4  = __attribute__((ext_vector_type(4))) float;
using bf16x8 = __attribute__((ext_vector_type(8))) __bf16;

#define KS (-1.442695041f)   // -log2(e)
#define KT (-2.885390082f)   // -2*log2(e)

__device__ __forceinline__ float bf2f(__bf16 b) {
  unsigned short s = __builtin_bit_cast(unsigned short, b);
  unsigned u = ((unsigned)s) << 16;
  return __builtin_bit_cast(float, u);
}
__device__ __forceinline__ float sig_u(float u) {   // sigmoid, u = KS*(x+b)
  return __builtin_amdgcn_rcpf(1.0f + __builtin_amdgcn_exp2f(u));
}
__device__ __forceinline__ float tanh_u(float u) {  // tanh, u = KT*(x+b)
  return 2.0f * __builtin_amdgcn_rcpf(1.0f + __builtin_amdgcn_exp2f(u)) - 1.0f;
}

#define MF(A, Bv, C) __builtin_amdgcn_mfma_f32_16x16x32_bf16((A), (Bv), (C), 0, 0, 0)
#define PIN_A(v) asm volatile("" : "+a"(v))

__device__ __forceinline__ bf16x8 ldw8(const float* p) {
  float4 v0 = *(const float4*)p;
  float4 v1 = *(const float4*)(p + 4);
  bf16x8 r;
  r[0] = (__bf16)v0.x; r[1] = (__bf16)v0.y; r[2] = (__bf16)v0.z; r[3] = (__bf16)v0.w;
  r[4] = (__bf16)v1.x; r[5] = (__bf16)v1.y; r[6] = (__bf16)v1.z; r[7] = (__bf16)v1.w;
  return r;
}

__global__ __launch_bounds__(512)
void lstm_kernel(const float* __restrict__ x,
                 const float* __restrict__ Wih0, const float* __restrict__ Whh0,
                 const float* __restrict__ bih0, const float* __restrict__ bhh0,
                 const float* __restrict__ Wih1, const float* __restrict__ Whh1,
                 const float* __restrict__ bih1, const float* __restrict__ bhh1,
                 const float* __restrict__ Wih2, const float* __restrict__ Whh2,
                 const float* __restrict__ bih2, const float* __restrict__ bhh2,
                 const float* __restrict__ Wfc, const float* __restrict__ bfc,
                 float* __restrict__ out) {
  __shared__ __align__(16) __bf16 h0s[2][16][72];
  __shared__ __align__(16) __bf16 h1s[2][16][72];
  __shared__ __align__(16) __bf16 h2s[2][16][136];
  __shared__ __align__(16) __bf16 wih2l[512][72];

  const int tid = threadIdx.x;
  const int w   = tid >> 6;      // wave 0..7
  const bool g01 = (w < 4);
  const int gw  = w & 3;
  const int l   = tid & 63;
  const int l15 = l & 15;
  const int lg  = l >> 4;
  const int k0  = lg * 8;
  const int r0  = blockIdx.x << 4;

  for (int i = tid; i < 2 * 16 * 72; i += 512) {
    (&h0s[0][0][0])[i] = __bf16(0.f);
    (&h1s[0][0][0])[i] = __bf16(0.f);
  }
  for (int i = tid; i < 2 * 16 * 136; i += 512) (&h2s[0][0][0])[i] = __bf16(0.f);
  for (int i = tid; i < 512 * 64; i += 512) {
    int row = i >> 6, col = i & 63;
    wih2l[row][col] = (__bf16)Wih2[i];
  }

  // ---- SHARED weight array (union across roles), pinned to AGPRs ----
  // G01: AG[0..3]=Wih0, AG[4..11]=Whh0, AG[12..19]=Wih1, AG[20..27]=Whh1
  // G23: AG[0..31]=Whh2 (s,gi,kk -> 16s+4gi+kk)
  bf16x8 AG[32];
#pragma unroll
  for (int i = 0; i < 32; ++i) AG[i] = bf16x8{};
  f32x4  AC[8];     // G01: AC[0..3] reused l0/l1; G23: AC[gi]=s0 (slot1-local), AC[4+gi]=s1 (lives across B1)
  float  BI[8];     // pre-scaled biases (gi==2 -> KT*b else KS*b)
  float  CS[8];     // cell states
#pragma unroll
  for (int i = 0; i < 8; ++i) CS[i] = 0.f;

  if (g01) {
#pragma unroll
    for (int gi = 0; gi < 4; ++gi) {
      const int row = 16 * (4 * gi + gw) + l15;
      AG[gi] = ldw8(Wih0 + (size_t)row * 32 + k0);
#pragma unroll
      for (int kb = 0; kb < 2; ++kb) {
        AG[4 + 2 * gi + kb]  = ldw8(Whh0 + (size_t)row * 64 + kb * 32 + k0);
        AG[12 + 2 * gi + kb] = ldw8(Wih1 + (size_t)row * 64 + kb * 32 + k0);
        AG[20 + 2 * gi + kb] = ldw8(Whh1 + (size_t)row * 64 + kb * 32 + k0);
      }
      const float sc = (gi == 2) ? KT : KS;
      const int c01 = 64 * gi + 16 * gw + l15;
      BI[gi]     = sc * (bih0[c01] + bhh0[c01]);
      BI[4 + gi] = sc * (bih1[c01] + bhh1[c01]);
    }
  } else {
#pragma unroll
    for (int s = 0; s < 2; ++s)
#pragma unroll
      for (int gi = 0; gi < 4; ++gi) {
        const int row = 16 * (8 * gi + 2 * gw + s) + l15;
#pragma unroll
        for (int kk = 0; kk < 4; ++kk)
          AG[16 * s + 4 * gi + kk] = ldw8(Whh2 + (size_t)row * 128 + kk * 32 + k0);
        const float sc = (gi == 2) ? KT : KS;
        const int c2 = 128 * gi + 32 * gw + 16 * s + l15;
        BI[4 * s + gi] = sc * (bih2[c2] + bhh2[c2]);
      }
  }
#pragma unroll
  for (int i = 0; i < 32; ++i) PIN_A(AG[i]);

  const float* xrow = x + (size_t)(r0 + l15) * 512 * 32 + k0;
  float4 nx0 = {0.f, 0.f, 0.f, 0.f}, nx1 = {0.f, 0.f, 0.f, 0.f};
  if (g01) { nx0 = *(const float4*)xrow; nx1 = *(const float4*)(xrow + 4); }

  const f32x4 Z0 = {0.f, 0.f, 0.f, 0.f};

  __syncthreads();

#pragma unroll 1
  for (int t = 0; t <= 512; ++t) {
    const int pb = t & 1, rb = pb ^ 1;

    // ---------------- slot 1 ----------------
    if (g01) {
      if (t < 512) {
        // layer0(t): h0(t) = cell(x(t), h0(t-1))
        float4 cx0 = nx0, cx1 = nx1;
        const int tn = (t + 1) & 511;
        nx0 = *(const float4*)(xrow + (size_t)tn * 32);
        nx1 = *(const float4*)(xrow + (size_t)tn * 32 + 4);

        bf16x8 ax;
        ax[0] = (__bf16)cx0.x; ax[1] = (__bf16)cx0.y; ax[2] = (__bf16)cx0.z; ax[3] = (__bf16)cx0.w;
        ax[4] = (__bf16)cx1.x; ax[5] = (__bf16)cx1.y; ax[6] = (__bf16)cx1.z; ax[7] = (__bf16)cx1.w;

        bf16x8 a0 = *(const bf16x8*)&h0s[rb][l15][k0];
        bf16x8 a1 = *(const bf16x8*)&h0s[rb][l15][32 + k0];
#pragma unroll
        for (int gi = 0; gi < 4; ++gi) {
          f32x4 a = Z0;
          a = MF(ax, AG[gi], a);
          a = MF(a0, AG[4 + 2 * gi], a);
          a = MF(a1, AG[5 + 2 * gi], a);
          AC[gi] = a;
        }
#pragma unroll
        for (int j = 0; j < 4; ++j) {
          float si = sig_u (fmaf(KS, AC[0][j], BI[0]));
          float sf = sig_u (fmaf(KS, AC[1][j], BI[1]));
          float tg = tanh_u(fmaf(KT, AC[2][j], BI[2]));
          float so = sig_u (fmaf(KS, AC[3][j], BI[3]));
          float nc = sf * CS[j] + si * tg;
          CS[j] = nc;
          h0s[pb][4 * lg + j][16 * gw + l15] = (__bf16)(so * tanh_u(KT * nc));
        }
      }
    } else {
      if (t >= 1) {
        // layer2(t-1): s=0 MFMA -> s=0 acts + write -> s=1 MFMA
        bf16x8 b0 = *(const bf16x8*)&h1s[rb][l15][k0];
        bf16x8 b1 = *(const bf16x8*)&h1s[rb][l15][32 + k0];
        bf16x8 d0 = *(const bf16x8*)&h2s[pb][l15][k0];
        bf16x8 d1 = *(const bf16x8*)&h2s[pb][l15][32 + k0];
        bf16x8 d2 = *(const bf16x8*)&h2s[pb][l15][64 + k0];
        bf16x8 d3 = *(const bf16x8*)&h2s[pb][l15][96 + k0];
        // s = 0 MFMA chain
#pragma unroll
        for (int gi = 0; gi < 4; ++gi) {
          const int tile = 8 * gi + 2 * gw;
          bf16x8 wa0 = *(const bf16x8*)&wih2l[16 * tile + l15][k0];
          bf16x8 wa1 = *(const bf16x8*)&wih2l[16 * tile + l15][32 + k0];
          f32x4 a = Z0;
          a = MF(b0, wa0, a);
          a = MF(b1, wa1, a);
          a = MF(d0, AG[4 * gi + 0], a);
          a = MF(d1, AG[4 * gi + 1], a);
          a = MF(d2, AG[4 * gi + 2], a);
          a = MF(d3, AG[4 * gi + 3], a);
          AC[gi] = a;
        }
        // s = 0 activations + h2 write (write side h2s[rb]; reads were h2s[pb])
#pragma unroll
        for (int j = 0; j < 4; ++j) {
          float si = sig_u (fmaf(KS, AC[0][j], BI[0]));
          float sf = sig_u (fmaf(KS, AC[1][j], BI[1]));
          float tg = tanh_u(fmaf(KT, AC[2][j], BI[2]));
          float so = sig_u (fmaf(KS, AC[3][j], BI[3]));
          float nc = sf * CS[j] + si * tg;
          CS[j] = nc;
          h2s[rb][4 * lg + j][32 * gw + l15] = (__bf16)(so * tanh_u(KT * nc));
        }
        // s = 1 MFMA chain (accumulators live across B1)
#pragma unroll
        for (int gi = 0; gi < 4; ++gi) {
          const int tile = 8 * gi + 2 * gw + 1;
          bf16x8 wa0 = *(const bf16x8*)&wih2l[16 * tile + l15][k0];
          bf16x8 wa1 = *(const bf16x8*)&wih2l[16 * tile + l15][32 + k0];
          f32x4 a = Z0;
          a = MF(b0, wa0, a);
          a = MF(b1, wa1, a);
          a = MF(d0, AG[16 + 4 * gi + 0], a);
          a = MF(d1, AG[16 + 4 * gi + 1], a);
          a = MF(d2, AG[16 + 4 * gi + 2], a);
          a = MF(d3, AG[16 + 4 * gi + 3], a);
          AC[4 + gi] = a;
        }
      }
    }
    __syncthreads();  // B1: h0(t) visible to G01-l1

    // ---------------- slot 2 ----------------
    if (g01) {
      if (t < 512) {
        // layer1(t): h1(t) = cell(h0(t), h1(t-1))
        bf16x8 a0 = *(const bf16x8*)&h0s[pb][l15][k0];
        bf16x8 a1 = *(const bf16x8*)&h0s[pb][l15][32 + k0];
        bf16x8 b0 = *(const bf16x8*)&h1s[rb][l15][k0];
        bf16x8 b1 = *(const bf16x8*)&h1s[rb][l15][32 + k0];
#pragma unroll
        for (int gi = 0; gi < 4; ++gi) {
          f32x4 a = Z0;
          a = MF(a0, AG[12 + 2 * gi], a);
          a = MF(a1, AG[13 + 2 * gi], a);
          a = MF(b0, AG[20 + 2 * gi], a);
          a = MF(b1, AG[21 + 2 * gi], a);
          AC[gi] = a;
        }
#pragma unroll
        for (int j = 0; j < 4; ++j) {
          float si = sig_u (fmaf(KS, AC[0][j], BI[4]));
          float sf = sig_u (fmaf(KS, AC[1][j], BI[5]));
          float tg = tanh_u(fmaf(KT, AC[2][j], BI[6]));
          float so = sig_u (fmaf(KS, AC[3][j], BI[7]));
          float nc = sf * CS[4 + j] + si * tg;
          CS[4 + j] = nc;
          h1s[pb][4 * lg + j][16 * gw + l15] = (__bf16)(so * tanh_u(KT * nc));
        }
      }
    } else {
      if (t >= 1) {
        // layer2(t-1): s=1 activations + write
#pragma unroll
        for (int j = 0; j < 4; ++j) {
          float si = sig_u (fmaf(KS, AC[4 + 0][j], BI[4]));
          float sf = sig_u (fmaf(KS, AC[4 + 1][j], BI[5]));
          float tg = tanh_u(fmaf(KT, AC[4 + 2][j], BI[6]));
          float so = sig_u (fmaf(KS, AC[4 + 3][j], BI[7]));
          float nc = sf * CS[4 + j] + si * tg;
          CS[4 + j] = nc;
          h2s[rb][4 * lg + j][32 * gw + 16 + l15] = (__bf16)(so * tanh_u(KT * nc));
        }
      }
    }
    __syncthreads();  // B2: h1(t), h2(t-1) visible
  }

  // ---- final FC: out = h2(511) @ Wfc^T + bfc;  h2(511) is in buffer 1 ----
  if (tid < 160) {
    const int r = tid / 10, o = tid - r * 10;
    float sum = bfc[o];
    for (int u = 0; u < 128; ++u) sum += bf2f(h2s[1][r][u]) * Wfc[o * 128 + u];
    out[(size_t)(r0 + r) * 10 + o] = sum;
  }
}

extern "C" void kernel_launch(void* const* d_in, const int* in_sizes, int n_in,
                              void* d_out, int out_size, void* d_ws, size_t ws_size,
                              hipStream_t stream) {
  const float* x    = (const float*)d_in[0];
  const float* Wih0 = (const float*)d_in[1];
  const float* Whh0 = (const float*)d_in[2];
  const float* bih0 = (const float*)d_in[3];
  const float* bhh0 = (const float*)d_in[4];
  const float* Wih1 = (const float*)d_in[5];
  const float* Whh1 = (const float*)d_in[6];
  const float* bih1 = (const float*)d_in[7];
  const float* bhh1 = (const float*)d_in[8];
  const float* Wih2 = (const float*)d_in[9];
  const float* Whh2 = (const float*)d_in[10];
  const float* bih2 = (const float*)d_in[11];
  const float* bhh2 = (const float*)d_in[12];
  const float* Wfc  = (const float*)d_in[13];
  const float* bfc  = (const float*)d_in[14];

  lstm_kernel<<<256, 512, 0, stream>>>(x, Wih0, Whh0, bih0, bhh0,
                                       Wih1, Whh1, bih1, bhh1,
                                       Wih2, Whh2, bih2, bhh2,
                                       Wfc, bfc, (float*)d_out);
}